// Round 15
// baseline (7465.038 us; speedup 1.0000x reference)
//
#include <hip/hip_runtime.h>

#define HSTEPS 8640
#define HID 128
#define BATCH 16
#define NTHR 1024
#define YRING 192
#define INV127 (1.0f / 127.0f)

typedef __attribute__((ext_vector_type(4))) int i32x4;

static __device__ __forceinline__ float sigm(float x) {
    return __builtin_amdgcn_rcpf(1.0f + __expf(-x));
}
template <int CTRL>
static __device__ __forceinline__ float dppmov(float x) {
    return __int_as_float(
        __builtin_amdgcn_mov_dpp(__float_as_int(x), CTRL, 0xF, 0xF, false));
}
// sum of 8-periodic values -> every lane holds its 8-group total
static __device__ __forceinline__ float sum8(float x) {
    x += dppmov<0x121>(x);
    x += dppmov<0x122>(x);
    x += dppmov<0x124>(x);
    return x;
}
// sum across each 16-lane row -> every lane holds its row's sum
static __device__ __forceinline__ float sum16(float x) {
    x += dppmov<0x121>(x);
    x += dppmov<0x122>(x);
    x += dppmov<0x124>(x);
    x += dppmov<0x128>(x);
    return x;
}
// wave64 max (values >= 0) -> lane 63 holds the wave max
static __device__ __forceinline__ float maxwave(float x) {
    x = fmaxf(x, dppmov<0x121>(x));
    x = fmaxf(x, dppmov<0x122>(x));
    x = fmaxf(x, dppmov<0x124>(x));
    x = fmaxf(x, dppmov<0x128>(x));
    float t1 = __int_as_float(__builtin_amdgcn_update_dpp(
        0, __float_as_int(x), 0x142, 0xA, 0xF, false));
    x = fmaxf(x, t1);
    float t2 = __int_as_float(__builtin_amdgcn_update_dpp(
        0, __float_as_int(x), 0x143, 0xC, 0xF, false));
    x = fmaxf(x, t2);
    return x;
}
// lane^16 exchange via ds_swizzle BitMode (quantrow reduction only)
static __device__ __forceinline__ float swzx16(float x) {
    return __int_as_float(
        __builtin_amdgcn_ds_swizzle(__float_as_int(x), 0x401F));
}

static __device__ __forceinline__ int pack4(const float* v, float inv) {
    int a = (int)__builtin_rintf(v[0] * inv);
    int b = (int)__builtin_rintf(v[1] * inv);
    int c = (int)__builtin_rintf(v[2] * inv);
    int d = (int)__builtin_rintf(v[3] * inv);
    return (a & 0xff) | ((b & 0xff) << 8) | ((c & 0xff) << 16) |
           ((d & 0xff) << 24);
}

// Quantize one gate row to i8 with a per-row scale.
static __device__ __forceinline__ void quantrow(const float* rp, int grp,
                                                i32x4& f0, i32x4& f1,
                                                float& sw) {
    float v[32];
#pragma unroll
    for (int j = 0; j < 16; ++j) v[j] = rp[16 * grp + j];
#pragma unroll
    for (int j = 0; j < 16; ++j) v[16 + j] = rp[64 + 16 * grp + j];
    float mx = 1e-20f;
#pragma unroll
    for (int j = 0; j < 32; ++j) mx = fmaxf(mx, __builtin_fabsf(v[j]));
    mx = fmaxf(mx, swzx16(mx));
    mx = fmaxf(mx, __shfl_xor(mx, 32, 64));
    float inv = 127.0f / mx;
    sw = mx * INV127;
    f0 = i32x4{pack4(v, inv), pack4(v + 4, inv), pack4(v + 8, inv),
               pack4(v + 12, inv)};
    f1 = i32x4{pack4(v + 16, inv), pack4(v + 20, inv), pack4(v + 24, inv),
               pack4(v + 28, inv)};
}

// Quantize the SAME row of two matrices with ONE shared scale.
static __device__ __forceinline__ void quantrow2(const float* rpA,
                                                 const float* rpB, int grp,
                                                 i32x4& a0, i32x4& a1,
                                                 i32x4& b0, i32x4& b1,
                                                 float& sw) {
    float vA[32], vB[32];
#pragma unroll
    for (int j = 0; j < 16; ++j) {
        vA[j] = rpA[16 * grp + j];
        vA[16 + j] = rpA[64 + 16 * grp + j];
        vB[j] = rpB[16 * grp + j];
        vB[16 + j] = rpB[64 + 16 * grp + j];
    }
    float mx = 1e-20f;
#pragma unroll
    for (int j = 0; j < 32; ++j) {
        mx = fmaxf(mx, __builtin_fabsf(vA[j]));
        mx = fmaxf(mx, __builtin_fabsf(vB[j]));
    }
    mx = fmaxf(mx, swzx16(mx));
    mx = fmaxf(mx, __shfl_xor(mx, 32, 64));
    float inv = 127.0f / mx;
    sw = mx * INV127;
    a0 = i32x4{pack4(vA, inv), pack4(vA + 4, inv), pack4(vA + 8, inv),
               pack4(vA + 12, inv)};
    a1 = i32x4{pack4(vA + 16, inv), pack4(vA + 20, inv), pack4(vA + 24, inv),
               pack4(vA + 28, inv)};
    b0 = i32x4{pack4(vB, inv), pack4(vB + 4, inv), pack4(vB + 8, inv),
               pack4(vB + 12, inv)};
    b1 = i32x4{pack4(vB + 16, inv), pack4(vB + 20, inv), pack4(vB + 24, inv),
               pack4(vB + 28, inv)};
}

#define CH2(Q, A0, A1, FA, FB)                                                \
    Q = __builtin_amdgcn_mfma_i32_16x16x64_i8((A0), FA, zqi, 0, 0, 0);        \
    Q = __builtin_amdgcn_mfma_i32_16x16x64_i8((A1), FB, (Q), 0, 0, 0);
#define CH2C(Q, A0, A1, FA, FB)                                               \
    Q = __builtin_amdgcn_mfma_i32_16x16x64_i8((A0), FA, (Q), 0, 0, 0);        \
    Q = __builtin_amdgcn_mfma_i32_16x16x64_i8((A1), FB, (Q), 0, 0, 0);

// 16 waves (4/SIMD @128-reg tier), role-split: waves 0-7 (X) = layer 0
// (Whh0, act0); waves 8-15 (Y) = layer 1 (Wih1+Whh1 merged-scale, act1+fc).
// Each wave owns 16 elements; lane's 4 gate accumulators are IN-LANE
// (chain g -> gate g of element e = 16*gw + (ln&15)): act has no cross-lane
// exchanges. i8 MFMA weights as AGPR frags (X: 32, Y: 64 regs). 4-way TLP
// per SIMD hides MFMA drain + act latency. 2 barriers/step.
__global__ __launch_bounds__(NTHR, 4) void lstm2_kernel(
    const float* __restrict__ y0, const float* __restrict__ h0in,
    const float* __restrict__ c0in, const float* __restrict__ Wih0,
    const float* __restrict__ Whh0, const float* __restrict__ bih0,
    const float* __restrict__ bhh0, const float* __restrict__ Wih1,
    const float* __restrict__ Whh1, const float* __restrict__ bih1,
    const float* __restrict__ bhh1, const float* __restrict__ fcw,
    const float* __restrict__ fcb, float* __restrict__ out) {
    const int b = blockIdx.x;
    const int t = threadIdx.x;
    const int wv = t >> 6;
    const int ln = t & 63;
    const int grp = ln >> 4;   // MFMA A k-slot (act values replicated x4)
    const int ln15 = ln & 15;
    const int gw = wv & 7;            // index within role group
    const bool isX = wv < 8;
    const int e = 16 * gw + ln15;     // this lane's element 0..127

    // hsm8 bytes: [0..127]=h0 buf0, [128..255]=h0 buf1,
    //             [256..383]=h1 buf0, [384..511]=h1 buf1
    __shared__ __align__(16) char hsm8[512];
    __shared__ float ypartbuf[8];
    __shared__ float maxb[16];
    __shared__ float ybuf[YRING];

    const i32x4 zqi = {0, 0, 0, 0};

    // ---- fragments: X: Whh0 rows 128g+e (8 frags); Y: Wih1+Whh1 rows
    //      128g+e with shared scale (16 frags) ----
    i32x4 FA0a = zqi, FA0b = zqi, FA1a = zqi, FA1b = zqi;
    i32x4 FA2a = zqi, FA2b = zqi, FA3a = zqi, FA3b = zqi;
    i32x4 FB0a = zqi, FB0b = zqi, FB1a = zqi, FB1b = zqi;
    i32x4 FB2a = zqi, FB2b = zqi, FB3a = zqi, FB3b = zqi;
    // accumulators: 4 gate chains
    i32x4 Q0 = zqi, Q1 = zqi, Q2 = zqi, Q3 = zqi;

    float S0 = 0, S1 = 0, S2 = 0, S3 = 0;      // raw row scales
    float SQ0 = 0, SQ1 = 0, SQ2 = 0, SQ3 = 0;  // live dequant scales
    float B0c = 0, B1c = 0, B2c = 0, B3c = 0;  // biases (gate 2 pre-x2)
    float E0c = 0, E1c = 0, E2c = 0, E3c = 0;  // X: Wih0 cols; Y: E0c=fcw
    float H0c = 0, H1c = 0, H2c = 0, H3c = 0;  // Y: step-0 Whh1 correction
    float Cst = 0;

    if (isX) {
        quantrow(Whh0 + (size_t)(e)*HID, grp, FA0a, FA0b, S0);
        quantrow(Whh0 + (size_t)(128 + e) * HID, grp, FA1a, FA1b, S1);
        quantrow(Whh0 + (size_t)(256 + e) * HID, grp, FA2a, FA2b, S2);
        quantrow(Whh0 + (size_t)(384 + e) * HID, grp, FA3a, FA3b, S3);
        B0c = bih0[e] + bhh0[e];
        B1c = bih0[128 + e] + bhh0[128 + e];
        B2c = 2.0f * (bih0[256 + e] + bhh0[256 + e]);  // tanh fold
        B3c = bih0[384 + e] + bhh0[384 + e];
        E0c = Wih0[e];
        E1c = Wih0[128 + e];
        E2c = 2.0f * Wih0[256 + e];
        E3c = Wih0[384 + e];
        S2 *= 2.0f;  // fold tanh 2x into gate-2 scale
        Cst = c0in[b * HID + e];
    } else {
        quantrow2(Wih1 + (size_t)(e)*HID, Whh1 + (size_t)(e)*HID, grp, FA0a,
                  FA0b, FB0a, FB0b, S0);
        quantrow2(Wih1 + (size_t)(128 + e) * HID,
                  Whh1 + (size_t)(128 + e) * HID, grp, FA1a, FA1b, FB1a,
                  FB1b, S1);
        quantrow2(Wih1 + (size_t)(256 + e) * HID,
                  Whh1 + (size_t)(256 + e) * HID, grp, FA2a, FA2b, FB2a,
                  FB2b, S2);
        quantrow2(Wih1 + (size_t)(384 + e) * HID,
                  Whh1 + (size_t)(384 + e) * HID, grp, FA3a, FA3b, FB3a,
                  FB3b, S3);
        B0c = bih1[e] + bhh1[e];
        B1c = bih1[128 + e] + bhh1[128 + e];
        B2c = 2.0f * (bih1[256 + e] + bhh1[256 + e]);
        B3c = bih1[384 + e] + bhh1[384 + e];
        S2 *= 2.0f;
        // live scales fixed from step 0 on (both h at 1/127)
        SQ0 = S0 * INV127;
        SQ1 = S1 * INV127;
        SQ2 = S2 * INV127;
        SQ3 = S3 * INV127;
        E0c = fcw[e];
        Cst = c0in[(BATCH + b) * HID + e];
    }

    const float fcb_ = fcb[0];

    // ---- prologue: stage initial h (dynamic block scales) ----
    float hv_ = 0.f;
    if (t < 128) hv_ = h0in[b * HID + t];
    else if (t < 256) hv_ = h0in[(BATCH + b) * HID + (t - 128)];
    float am = maxwave(__builtin_fabsf(hv_));
    if (ln == 63) maxb[wv] = am;
    if (t < 8) ypartbuf[t] = (t == 0) ? (y0[b] - fcb_) : 0.0f;
    __syncthreads();
    const float bm0 = fmaxf(fmaxf(maxb[0], maxb[1]), 1e-20f);
    const float bm1 = fmaxf(fmaxf(maxb[2], maxb[3]), 1e-20f);
    if (t < 128)
        hsm8[t] = (char)(int)__builtin_rintf(hv_ * (127.0f / bm0));
    else if (t < 256)
        hsm8[256 + (t - 128)] = (char)(int)__builtin_rintf(hv_ * (127.0f / bm1));
    __syncthreads();

    float* outb = out + (size_t)b * HSTEPS;

    if (isX) {
        // step-0 live scales carry the initial-h0 block scale
        float s0i = bm0 * INV127;
        SQ0 = S0 * s0i;
        SQ1 = S1 * s0i;
        SQ2 = S2 * s0i;
        SQ3 = S3 * s0i;
        // X preamble: Q = Whh0 @ h0_in(0)
        i32x4 a0 = *(const i32x4*)&hsm8[16 * grp];
        i32x4 a1 = *(const i32x4*)&hsm8[64 + 16 * grp];
        CH2(Q0, a0, a1, FA0a, FA0b)
        CH2(Q1, a0, a1, FA1a, FA1b)
        CH2(Q2, a0, a1, FA2a, FA2b)
        CH2(Q3, a0, a1, FA3a, FA3b)
    } else {
        // Y preamble: throwaway Whh1 @ h1_init -> float corrections H*c
        i32x4 b0_ = *(const i32x4*)&hsm8[256 + 16 * grp];
        i32x4 b1_ = *(const i32x4*)&hsm8[256 + 64 + 16 * grp];
        i32x4 T0, T1, T2, T3;
        CH2(T0, b0_, b1_, FB0a, FB0b)
        CH2(T1, b0_, b1_, FB1a, FB1b)
        CH2(T2, b0_, b1_, FB2a, FB2b)
        CH2(T3, b0_, b1_, FB3a, FB3b)
        float s1i = bm1 * INV127;
        H0c = S0 * s1i * (float)T0[0];
        H1c = S1 * s1i * (float)T1[0];
        H2c = S2 * s1i * (float)T2[0];
        H3c = S3 * s1i * (float)T3[0];
        Q0 = zqi; Q1 = zqi; Q2 = zqi; Q3 = zqi;
    }

    int p = 0;
    int ys = 0;
    int flush_at = YRING;

#pragma unroll 1
    for (int s = 0; s < HSTEPS; ++s) {
        // ================= half 1 =================
        if (isX) {
            // y(s-1); act0(s) [Q from half2(s-1)]; publish h0_out(s)
            float yv = sum8(ypartbuf[ln & 7]) + fcb_;
            if (s > 0) {
                if (t == 0) ybuf[ys] = yv;
                ys = (ys == YRING - 1) ? 0 : ys + 1;
            }
            float G0 = __builtin_fmaf(SQ0, (float)Q0[0],
                                      __builtin_fmaf(E0c, yv, B0c));
            float G1 = __builtin_fmaf(SQ1, (float)Q1[0],
                                      __builtin_fmaf(E1c, yv, B1c));
            float G2 = __builtin_fmaf(SQ2, (float)Q2[0],
                                      __builtin_fmaf(E2c, yv, B2c));
            float G3 = __builtin_fmaf(SQ3, (float)Q3[0],
                                      __builtin_fmaf(E3c, yv, B3c));
            float si = sigm(G0), sf = sigm(G1), so = sigm(G3);
            float tg = __builtin_fmaf(2.f, sigm(G2), -1.f);  // tanh (folded)
            Cst = __builtin_fmaf(sf, Cst, si * tg);
            float h0n = so * __builtin_fmaf(2.f, sigm(2.f * Cst), -1.f);
            if (ln < 16)
                hsm8[(p ^ 1) * 128 + e] =
                    (char)(int)__builtin_rintf(h0n * 127.0f);
            if (s == 0) {
                SQ0 = S0 * INV127;
                SQ1 = S1 * INV127;
                SQ2 = S2 * INV127;
                SQ3 = S3 * INV127;
            }
        } else if (s > 0) {
            // Q = Whh1 @ h1_in(s)
            const char* h1p = hsm8 + 256 + 128 * p + 16 * grp;
            i32x4 b0_ = *(const i32x4*)(h1p);
            i32x4 b1_ = *(const i32x4*)(h1p + 64);
            CH2(Q0, b0_, b1_, FB0a, FB0b)
            CH2(Q1, b0_, b1_, FB1a, FB1b)
            CH2(Q2, b0_, b1_, FB2a, FB2b)
            CH2(Q3, b0_, b1_, FB3a, FB3b)
        }
        __syncthreads();  // B1: h0_out(s) ready

        // ================= half 2 =================
        if (isX) {
            if (s == flush_at) {
                if (t < YRING) outb[flush_at - YRING + t] = ybuf[t];
                flush_at += YRING;
            }
            // Q = Whh0 @ h0_out(s)  (pre-work for step s+1)
            const char* h0np = hsm8 + (p ^ 1) * 128 + 16 * grp;
            i32x4 d0 = *(const i32x4*)(h0np);
            i32x4 d1 = *(const i32x4*)(h0np + 64);
            CH2(Q0, d0, d1, FA0a, FA0b)
            CH2(Q1, d0, d1, FA1a, FA1b)
            CH2(Q2, d0, d1, FA2a, FA2b)
            CH2(Q3, d0, d1, FA3a, FA3b)
        } else {
            __builtin_amdgcn_s_setprio(1);
            // Q += Wih1 @ h0_out(s); act1; publish h1_out(s), y-partial
            const char* h0np = hsm8 + (p ^ 1) * 128 + 16 * grp;
            i32x4 d0 = *(const i32x4*)(h0np);
            i32x4 d1 = *(const i32x4*)(h0np + 64);
            CH2C(Q0, d0, d1, FA0a, FA0b)
            CH2C(Q1, d0, d1, FA1a, FA1b)
            CH2C(Q2, d0, d1, FA2a, FA2b)
            CH2C(Q3, d0, d1, FA3a, FA3b)
            float H0 = __builtin_fmaf(SQ0, (float)Q0[0], B0c + H0c);
            float H1 = __builtin_fmaf(SQ1, (float)Q1[0], B1c + H1c);
            float H2 = __builtin_fmaf(SQ2, (float)Q2[0], B2c + H2c);
            float H3 = __builtin_fmaf(SQ3, (float)Q3[0], B3c + H3c);
            float ti = sigm(H0), tf = sigm(H1), to = sigm(H3);
            float tg1 = __builtin_fmaf(2.f, sigm(H2), -1.f);
            Cst = __builtin_fmaf(tf, Cst, ti * tg1);
            float h1n = to * __builtin_fmaf(2.f, sigm(2.f * Cst), -1.f);
            __builtin_amdgcn_s_setprio(0);
            if (ln < 16)
                hsm8[256 + (p ^ 1) * 128 + e] =
                    (char)(int)__builtin_rintf(h1n * 127.0f);
            // fc partial for this wave's 16 elements (replicated rows)
            float part = sum16(E0c * h1n);
            if (ln == 0) ypartbuf[gw] = part;
            if (s == 0) {
                H0c = 0.f;
                H1c = 0.f;
                H2c = 0.f;
                H3c = 0.f;
            }
        }
        __syncthreads();  // B2: h1_out(s) + ypart ready
        p ^= 1;
    }

    // ---- tail: y(8639) + final flush ----
    if (isX) {
        float yv = sum8(ypartbuf[ln & 7]) + fcb_;
        if (t == 0) ybuf[YRING - 1] = yv;
    }
    __syncthreads();
    if (t < YRING) outb[HSTEPS - YRING + t] = ybuf[t];
}

extern "C" void kernel_launch(void* const* d_in, const int* in_sizes, int n_in,
                              void* d_out, int out_size, void* d_ws,
                              size_t ws_size, hipStream_t stream) {
    const float* y0 = (const float*)d_in[0];
    const float* h0 = (const float*)d_in[1];
    const float* c0 = (const float*)d_in[2];
    const float* Wih0 = (const float*)d_in[3];
    const float* Whh0 = (const float*)d_in[4];
    const float* bih0 = (const float*)d_in[5];
    const float* bhh0 = (const float*)d_in[6];
    const float* Wih1 = (const float*)d_in[7];
    const float* Whh1 = (const float*)d_in[8];
    const float* bih1 = (const float*)d_in[9];
    const float* bhh1 = (const float*)d_in[10];
    const float* fcw = (const float*)d_in[11];
    const float* fcb = (const float*)d_in[12];
    float* out = (float*)d_out;

    lstm2_kernel<<<dim3(BATCH), dim3(NTHR), 0, stream>>>(
        y0, h0, c0, Wih0, Whh0, bih0, bhh0, Wih1, Whh1, bih1, bhh1, fcw, fcb,
        out);
}